// Round 18
// baseline (232.155 us; speedup 1.0000x reference)
//
#include <hip/hip_runtime.h>
#include <math.h>

#define TOTAL   8192
#define GENES   5000
#define NDS     64          // points per cloud
#define NB      128         // TOTAL / NDS
#define NSHARED 128
#define KC      64          // K-chunk staged in LDS
#define GP      5120        // padded gene count (4 x 1280) for bf16 buffer

// ws layout (floats): [0]=gene acc, [1]=cell acc, [48]=done (int),
// grams at GRAM_OFF; bf16 buffers after grams (new path only)
#define GRAM_OFF 64

typedef __attribute__((ext_vector_type(8)))  short        short8;
typedef __attribute__((ext_vector_type(4)))  unsigned int uint4v;
typedef __attribute__((ext_vector_type(16))) float        f32x16;

typedef const __attribute__((address_space(1))) void* GPTR;
typedef __attribute__((address_space(3))) void*       LPTR;

#define GLOAD16(gp, lp) \
    __builtin_amdgcn_global_load_lds((GPTR)(gp), (LPTR)(lp), 16, 0, 0)

// ---- fp32 -> bf16 round-half-up, packed pairwise (bitwise-identical to the
//      values rounds 9-16 fed MFMA; absmax ~0 vs 3.6e-2 threshold). ----
static __device__ inline unsigned int hpack2(float f0, float f1) {
    const unsigned int u0 = __builtin_bit_cast(unsigned int, f0) + 0x8000u;
    const unsigned int u1 = __builtin_bit_cast(unsigned int, f1) + 0x8000u;
    return (u1 & 0xFFFF0000u) | (u0 >> 16);
}
static __device__ inline short8 ldcvt_h(const float* base, int sw, int c0) {
    const float4 a = *(const float4*)(base + (((c0    ) ^ sw) << 2));
    const float4 b = *(const float4*)(base + (((c0 + 1) ^ sw) << 2));
    uint4v hv;
    hv[0] = hpack2(a.x, a.y); hv[1] = hpack2(a.z, a.w);
    hv[2] = hpack2(b.x, b.y); hv[3] = hpack2(b.z, b.w);
    return __builtin_bit_cast(short8, hv);
}

// ---- shared cell-level path (identical in both kernels) ----
static __device__ inline void cell_path(const float* __restrict__ X,
                                        const float* __restrict__ Y,
                                        float* __restrict__ acc,
                                        float* lds, int t) {
    const int s   = blockIdx.x;
    const int col = GENES - NSHARED + s;
#pragma unroll
    for (int k = 0; k < 32; ++k) {
        const int idx = t + 256 * k;
        lds[idx]        = X[(size_t)idx * GENES + col];
        lds[8192 + idx] = Y[(size_t)idx * GENES + col];
    }
    __syncthreads();
    const int ti = t & 15, tj = t >> 4;
    const int i0 = ti << 2, j0 = tj << 2;
    float axy[4][4] = {{0}}, axx[4][4] = {{0}}, ayy[4][4] = {{0}};
#pragma unroll 4
    for (int bb = 0; bb < NB; ++bb) {
        const float4 xi4 = *(const float4*)(lds + bb * 64 + i0);
        const float4 xj4 = *(const float4*)(lds + bb * 64 + j0);
        const float4 yi4 = *(const float4*)(lds + 8192 + bb * 64 + i0);
        const float4 yj4 = *(const float4*)(lds + 8192 + bb * 64 + j0);
        const float* xi = &xi4.x;
        const float* xj = &xj4.x;
        const float* yi = &yi4.x;
        const float* yj = &yj4.x;
#pragma unroll
        for (int ii = 0; ii < 4; ++ii)
#pragma unroll
            for (int jj = 0; jj < 4; ++jj) {
                axy[ii][jj] = fmaf(xi[ii], yj[jj], axy[ii][jj]);
                axx[ii][jj] = fmaf(xi[ii], xj[jj], axx[ii][jj]);
                ayy[ii][jj] = fmaf(yi[ii], yj[jj], ayy[ii][jj]);
            }
    }
    __syncthreads();
#pragma unroll
    for (int ii = 0; ii < 4; ++ii) {
        float4 v;
        v.x = axy[ii][0]; v.y = axy[ii][1]; v.z = axy[ii][2]; v.w = axy[ii][3];
        *(float4*)(lds + 0 * 4096 + (i0 + ii) * 64 + j0) = v;
        v.x = axx[ii][0]; v.y = axx[ii][1]; v.z = axx[ii][2]; v.w = axx[ii][3];
        *(float4*)(lds + 1 * 4096 + (i0 + ii) * 64 + j0) = v;
        v.x = ayy[ii][0]; v.y = ayy[ii][1]; v.z = ayy[ii][2]; v.w = ayy[ii][3];
        *(float4*)(lds + 2 * 4096 + (i0 + ii) * 64 + j0) = v;
    }
    __syncthreads();
    float local = 0.f;
#pragma unroll
    for (int k = 0; k < 16; ++k) {
        const int e = t + 256 * k;
        const int i = e >> 6, j = e & 63;
        const float gxy = lds[e];
        const float gxx = lds[4096 + e];
        const float gyy = lds[8192 + e];
        const float nxi = lds[4096 + i * 65], nxj = lds[4096 + j * 65];
        const float nyi = lds[8192 + i * 65], nyj = lds[8192 + j * 65];
        const float dxy = sqrtf(fmaxf(nxi + nyj - 2.f * gxy, 0.f));
        const float dxx = sqrtf(fmaxf(nxi + nxj - 2.f * gxx, 0.f));
        const float dyy = sqrtf(fmaxf(nyi + nyj - 2.f * gyy, 0.f));
        local += dxy - 0.5f * (dxx + dyy);
    }
#pragma unroll
    for (int off = 32; off; off >>= 1) local += __shfl_down(local, off);
    __syncthreads();
    if ((t & 63) == 0) lds[t >> 6] = local;
    __syncthreads();
    if (t == 0) {
        const float bl = lds[0] + lds[1] + lds[2] + lds[3];
        atomicAdd(acc + 1, bl * (1.0f / (4096.0f * (float)NSHARED)));
    }
}

// ---- shared gram writeout (verified 32x32 C/D layout) ----
static __device__ inline void gram_writeout(float* g, int qr, int qc, int lane,
                                            const f32x16 axy, const f32x16 axx,
                                            const f32x16 ayy) {
    const int col = (qc << 5) + (lane & 31);
#pragma unroll
    for (int r = 0; r < 16; ++r) {
        const int row = (qr << 5) + (r & 3) + ((r >> 2) << 3) + ((lane >> 5) << 2);
        g[0 * 4096 + row * 64 + col] = axy[r];
        g[1 * 4096 + row * 64 + col] = axx[r];
        g[2 * 4096 + row * 64 + col] = ayy[r];
    }
}

// ---------------------------------------------------------------------------
// NEW path (round-18: row coverage FIXED — round 17 only converted/staged
// rows 0-31, MFMA read uninitialized LDS for rows 32-63 -> NaN).
// Phase 1: free-running fp32->bf16 convert (no barriers) into L3-resident
// padded buffer. Phase 2: barrier-synced chunk loop stages bf16 from L3
// (half bytes, ~4x lower latency than HBM -> attacks the delivery cap).
// ---------------------------------------------------------------------------
__global__ __launch_bounds__(256, 2)
void k_main_bf16(const float* __restrict__ X, const float* __restrict__ Y,
                 unsigned short* __restrict__ bfX,
                 unsigned short* __restrict__ bfY,
                 float* __restrict__ grams, float* __restrict__ acc,
                 int splitD, int Dper) {
    __shared__ __align__(16) float smem[16384];   // 64 KB
    const int t = threadIdx.x;

    if ((int)blockIdx.x < NSHARED) { cell_path(X, Y, acc, smem, t); return; }

    const int blk = blockIdx.x - NSHARED;
    const int b = blk / splitD, c = blk % splitD;
    const int d0 = c * Dper;
    const int d1 = min(GENES, d0 + Dper);

    const int lane = t & 63;
    const int w    = t >> 6;
    const int qr   = w >> 1, qc = w & 1;
    const int lm   = lane & 31;
    const int kh   = lane >> 5;            // k-half 0/1

    const int mr = (qr << 5) + lm;
    const int mc = (qc << 5) + lm;

    // ================= convert phase (free-running, no barriers) ==========
    // wave w converts rows 16w..16w+15 of its (b, c) column slice.
    {
        const float* xb = X + (size_t)b * NDS * GENES;
        const float* yb = Y + (size_t)b * NDS * GENES;
        unsigned short* bxb = bfX + (size_t)b * NDS * GP;
        unsigned short* byb = bfY + (size_t)b * NDS * GP;
        for (int rr = 0; rr < 16; ++rr) {
            const int row = (w << 4) + rr;
            const float* sx = xb + (size_t)row * GENES;
            const float* sy = yb + (size_t)row * GENES;
            unsigned short* dx = bxb + (size_t)row * GP;
            unsigned short* dy = byb + (size_t)row * GP;
#pragma unroll
            for (int j = 0; j < 5; ++j) {          // 5 x 64 lanes x 4 = 1280
                const int col = d0 + ((lane + (j << 6)) << 2);
                float4 vx = {0.f, 0.f, 0.f, 0.f};
                float4 vy = {0.f, 0.f, 0.f, 0.f};
                if (col + 4 <= GENES) {            // pad region stores zeros
                    vx = *(const float4*)(sx + col);
                    vy = *(const float4*)(sy + col);
                }
                uint2 ux, uy;
                ux.x = hpack2(vx.x, vx.y); ux.y = hpack2(vx.z, vx.w);
                uy.x = hpack2(vy.x, vy.y); uy.y = hpack2(vy.z, vy.w);
                *(uint2*)(dx + col) = ux;
                *(uint2*)(dy + col) = uy;
            }
        }
    }
    __syncthreads();   // vmcnt(0): my slice writes complete (L2-visible)

    // ================= chunk loop (bf16, L3-fed) ==========================
    unsigned short* sXb = (unsigned short*)smem;          // [2][64][64] 16 KB
    unsigned short* sYb = (unsigned short*)smem + 8192;   // 16 KB

    // staging: 2 gloads/wave/array per chunk. lane l -> row 16w+(l>>3) (+8),
    // slot l&7; source pre-swizzled gene-block g = (l&7)^(l>>3).
    // rowB = rowA+8 has rowB&7 == rowA&7, so gblk is shared.
    const int srow = lane >> 3;
    const int gblk = (lane & 7) ^ srow;
    const int rowA = (w << 4) + srow;
    const unsigned short* gxA = bfX + ((size_t)b * NDS + rowA) * GP + gblk * 8;
    const unsigned short* gyA = bfY + ((size_t)b * NDS + rowA) * GP + gblk * 8;
    const unsigned short* gxB = gxA + 8 * GP;
    const unsigned short* gyB = gyA + 8 * GP;
    const int lA = w << 10;                // wave's LDS ushort base (16 rows)

#define STAGEBUF(bofs, dd) do {                          \
    GLOAD16(gxA + (dd), sXb + (bofs) + lA);              \
    GLOAD16(gxB + (dd), sXb + (bofs) + lA + 512);        \
    GLOAD16(gyA + (dd), sYb + (bofs) + lA);              \
    GLOAD16(gyB + (dd), sYb + (bofs) + lA + 512);        \
} while (0)

    f32x16 axy = {0,0,0,0,0,0,0,0,0,0,0,0,0,0,0,0};
    f32x16 axx = {0,0,0,0,0,0,0,0,0,0,0,0,0,0,0,0};
    f32x16 ayy = {0,0,0,0,0,0,0,0,0,0,0,0,0,0,0,0};

    const int nchunks = (d1 - d0 + KC - 1) / KC;

    STAGEBUF(0, d0);
    __syncthreads();

    for (int ci = 0; ci < nchunks; ++ci) {
        const int bofs = (ci & 1) << 12;   // 4096 ushorts per buffer
        if (ci + 1 < nchunks)
            STAGEBUF(((ci + 1) & 1) << 12, d0 + (ci + 1) * KC);
#pragma unroll
        for (int ks = 0; ks < 4; ++ks) {
            const int ls = (ks << 1) + kh;               // logical 16B slot
            const int er = bofs + (mr << 6) + ((ls ^ (mr & 7)) << 3);
            const int ec = bofs + (mc << 6) + ((ls ^ (mc & 7)) << 3);
            const short8 xr = *(const short8*)&sXb[er];
            const short8 yr = *(const short8*)&sYb[er];
            const short8 xc = *(const short8*)&sXb[ec];
            const short8 yc = *(const short8*)&sYb[ec];
            axy = __builtin_amdgcn_mfma_f32_32x32x16_bf16(xr, yc, axy, 0, 0, 0);
            axx = __builtin_amdgcn_mfma_f32_32x32x16_bf16(xr, xc, axx, 0, 0, 0);
            ayy = __builtin_amdgcn_mfma_f32_32x32x16_bf16(yr, yc, ayy, 0, 0, 0);
        }
        __syncthreads();
    }
#undef STAGEBUF

    gram_writeout(grams + (size_t)(b * splitD + c) * 3 * 4096,
                  qr, qc, lane, axy, axx, ayy);
}

// ---------------------------------------------------------------------------
// FALLBACK path: round-16 k_main verbatim (fp32 gload_lds staging) — used
// when ws is too small for the bf16 buffer. Known-good at ~138us.
// ---------------------------------------------------------------------------
__global__ __launch_bounds__(256, 2)
void k_main_f32(const float* __restrict__ X, const float* __restrict__ Y,
                const float* __restrict__ zsrc, float* __restrict__ grams,
                float* __restrict__ acc, int splitD, int Dper) {
    __shared__ __align__(16) float smem[16384];
    const int t = threadIdx.x;

    if ((int)blockIdx.x < NSHARED) { cell_path(X, Y, acc, smem, t); return; }

    const int blk = blockIdx.x - NSHARED;
    const int b = blk / splitD, c = blk % splitD;
    const int d0 = c * Dper;
    const int d1 = min(GENES, d0 + Dper);

    const float* __restrict__ xb = X + (size_t)b * NDS * GENES;
    const float* __restrict__ yb = Y + (size_t)b * NDS * GENES;

    float* sX = smem;
    float* sY = smem + 2 * NDS * KC;

    const int lane = t & 63;
    const int w    = t >> 6;
    const int qr   = w >> 1, qc = w & 1;
    const int lm   = lane & 31;
    const int kh2  = (lane >> 5) << 1;

    const int mr  = (qr << 5) + lm;
    const int mc  = (qc << 5) + lm;
    const int swr = mr & 15, swc = mc & 15;

    const int s16  = lane & 15;
    const int rsub = lane >> 4;
    const int rA = (w << 4) + rsub;
    const int rB = rA + 4, rC = rA + 8, rD = rA + 12;
    const int cA = (s16 ^ (rA & 15)) << 2;
    const int cB = (s16 ^ (rB & 15)) << 2;
    const int cC = (s16 ^ (rC & 15)) << 2;
    const int cD = (s16 ^ (rD & 15)) << 2;
    const float* gxA = xb + (size_t)rA * GENES + cA;
    const float* gxB = xb + (size_t)rB * GENES + cB;
    const float* gxC = xb + (size_t)rC * GENES + cC;
    const float* gxD = xb + (size_t)rD * GENES + cD;
    const float* gyA = yb + (size_t)rA * GENES + cA;
    const float* gyB = yb + (size_t)rB * GENES + cB;
    const float* gyC = yb + (size_t)rC * GENES + cC;
    const float* gyD = yb + (size_t)rD * GENES + cD;
    const int lA = ((w << 4) + 0) * KC;
    const int lB = lA + 4 * KC, lC = lA + 8 * KC, lD = lA + 12 * KC;

#define STAGEBUF(bofs, dd) do {                                               \
    const float* pxA = ((dd) + cA + 4 <= d1) ? gxA + (dd) : zsrc;             \
    const float* pxB = ((dd) + cB + 4 <= d1) ? gxB + (dd) : zsrc;             \
    const float* pxC = ((dd) + cC + 4 <= d1) ? gxC + (dd) : zsrc;             \
    const float* pxD = ((dd) + cD + 4 <= d1) ? gxD + (dd) : zsrc;             \
    const float* pyA = ((dd) + cA + 4 <= d1) ? gyA + (dd) : zsrc;             \
    const float* pyB = ((dd) + cB + 4 <= d1) ? gyB + (dd) : zsrc;             \
    const float* pyC = ((dd) + cC + 4 <= d1) ? gyC + (dd) : zsrc;             \
    const float* pyD = ((dd) + cD + 4 <= d1) ? gyD + (dd) : zsrc;             \
    GLOAD16(pxA, sX + (bofs) + lA);                                           \
    GLOAD16(pxB, sX + (bofs) + lB);                                           \
    GLOAD16(pxC, sX + (bofs) + lC);                                           \
    GLOAD16(pxD, sX + (bofs) + lD);                                           \
    GLOAD16(pyA, sY + (bofs) + lA);                                           \
    GLOAD16(pyB, sY + (bofs) + lB);                                           \
    GLOAD16(pyC, sY + (bofs) + lC);                                           \
    GLOAD16(pyD, sY + (bofs) + lD);                                           \
} while (0)

    f32x16 axy = {0,0,0,0,0,0,0,0,0,0,0,0,0,0,0,0};
    f32x16 axx = {0,0,0,0,0,0,0,0,0,0,0,0,0,0,0,0};
    f32x16 ayy = {0,0,0,0,0,0,0,0,0,0,0,0,0,0,0,0};

    const int nchunks = (d1 - d0 + KC - 1) / KC;

    STAGEBUF(0, d0);
    __syncthreads();

    for (int ci = 0; ci < nchunks; ++ci) {
        const int bofs = (ci & 1) * (NDS * KC);
        if (ci + 1 < nchunks)
            STAGEBUF(((ci + 1) & 1) * (NDS * KC), d0 + (ci + 1) * KC);

        const float* xrow = sX + bofs + mr * KC;
        const float* yrow = sY + bofs + mr * KC;
        const float* xcol = sX + bofs + mc * KC;
        const float* ycol = sY + bofs + mc * KC;
#pragma unroll
        for (int ks = 0; ks < 4; ++ks) {
            const int c0 = (ks << 2) + kh2;
            const short8 xr = ldcvt_h(xrow, swr, c0);
            const short8 yr = ldcvt_h(yrow, swr, c0);
            const short8 xc = ldcvt_h(xcol, swc, c0);
            const short8 yc = ldcvt_h(ycol, swc, c0);
            axy = __builtin_amdgcn_mfma_f32_32x32x16_bf16(xr, yc, axy, 0, 0, 0);
            axx = __builtin_amdgcn_mfma_f32_32x32x16_bf16(xr, xc, axx, 0, 0, 0);
            ayy = __builtin_amdgcn_mfma_f32_32x32x16_bf16(yr, yc, ayy, 0, 0, 0);
        }
        __syncthreads();
    }
#undef STAGEBUF

    gram_writeout(grams + (size_t)(b * splitD + c) * 3 * 4096,
                  qr, qc, lane, axy, axx, ayy);
}

// ---------------------------------------------------------------------------
// K2: reduce Gram partials, distances, accumulate; last block writes out.
// ---------------------------------------------------------------------------
__global__ __launch_bounds__(256) void k_gene_dist(const float* __restrict__ grams,
                                                   float* __restrict__ acc,
                                                   int* __restrict__ done,
                                                   float* __restrict__ out,
                                                   int splitD) {
    const int b = blockIdx.x, t = threadIdx.x;
    __shared__ __align__(16) float G[3 * 4096];
    __shared__ float red[4];

    for (int m = 0; m < 3; ++m) {
#pragma unroll
        for (int k = 0; k < 16; ++k) {
            const int e = t + 256 * k;
            float s = 0.f;
            for (int c = 0; c < splitD; ++c)
                s += grams[((size_t)(b * splitD + c) * 3 + m) * 4096 + e];
            G[m * 4096 + e] = s;
        }
    }
    __syncthreads();

    float local = 0.f;
#pragma unroll
    for (int k = 0; k < 16; ++k) {
        const int e = t + 256 * k;
        const int i = e >> 6, j = e & 63;
        const float gxy = G[e];
        const float gxx = G[4096 + e];
        const float gyy = G[8192 + e];
        const float nxi = G[4096 + i * 65], nxj = G[4096 + j * 65];
        const float nyi = G[8192 + i * 65], nyj = G[8192 + j * 65];
        const float dxy = sqrtf(fmaxf(nxi + nyj - 2.f * gxy, 0.f));
        const float dxx = sqrtf(fmaxf(nxi + nxj - 2.f * gxx, 0.f));
        const float dyy = sqrtf(fmaxf(nyi + nyj - 2.f * gyy, 0.f));
        local += dxy - 0.5f * (dxx + dyy);
    }
#pragma unroll
    for (int off = 32; off; off >>= 1) local += __shfl_down(local, off);
    if ((t & 63) == 0) red[t >> 6] = local;
    __syncthreads();
    if (t == 0) {
        const float bl = red[0] + red[1] + red[2] + red[3];
        atomicAdd(acc, bl * (1.0f / (4096.0f * (float)NB)));
        __threadfence();
        const int old = __hip_atomic_fetch_add(done, 1, __ATOMIC_ACQ_REL,
                                               __HIP_MEMORY_SCOPE_AGENT);
        if (old == NB - 1) {
            const float a0 = __hip_atomic_load(acc, __ATOMIC_RELAXED,
                                               __HIP_MEMORY_SCOPE_AGENT);
            const float a1 = __hip_atomic_load(acc + 1, __ATOMIC_RELAXED,
                                               __HIP_MEMORY_SCOPE_AGENT);
            out[0] = a0 + a1;
        }
    }
}

extern "C" void kernel_launch(void* const* d_in, const int* in_sizes, int n_in,
                              void* d_out, int out_size, void* d_ws, size_t ws_size,
                              hipStream_t stream) {
    const float* X = (const float*)d_in[0];
    const float* Y = (const float*)d_in[1];
    float* out = (float*)d_out;
    float* ws  = (float*)d_ws;

    int splitD = 4;
    while (splitD > 1 &&
           ((size_t)GRAM_OFF + (size_t)splitD * NB * 3 * 4096) * sizeof(float) > ws_size)
        splitD >>= 1;
    const int chunks = (GENES + KC - 1) / KC;            // 79
    const int cper   = (chunks + splitD - 1) / splitD;   // 20 at splitD=4
    const int Dper   = cper * KC;                        // 1280

    float* acc   = ws;
    float* zsrc  = ws + 32;
    int*   done  = (int*)(ws + 48);
    float* grams = ws + GRAM_OFF;

    const size_t gramFloats = (size_t)GRAM_OFF + (size_t)splitD * NB * 3 * 4096;
    const size_t bfCount    = (size_t)TOTAL * GP;        // ushorts per array
    const size_t needNew    = gramFloats * sizeof(float)
                            + 2 * bfCount * sizeof(unsigned short);

    hipMemsetAsync(ws, 0, GRAM_OFF * sizeof(float), stream);

    if (splitD == 4 && Dper == 1280 && ws_size >= needNew) {
        unsigned short* bfX = (unsigned short*)(ws + gramFloats);
        unsigned short* bfY = bfX + bfCount;
        hipLaunchKernelGGL(k_main_bf16, dim3(NSHARED + NB * splitD), dim3(256),
                           0, stream, X, Y, bfX, bfY, grams, acc, splitD, Dper);
    } else {
        hipLaunchKernelGGL(k_main_f32, dim3(NSHARED + NB * splitD), dim3(256),
                           0, stream, X, Y, zsrc, grams, acc, splitD, Dper);
    }
    hipLaunchKernelGGL(k_gene_dist, dim3(NB), dim3(256), 0, stream,
                       grams, acc, done, out, splitD);
}

// Round 19
// 160.652 us; speedup vs baseline: 1.4451x; 1.4451x over previous
//
#include <hip/hip_runtime.h>
#include <math.h>

#define TOTAL   8192
#define GENES   5000
#define NDS     64          // points per cloud
#define NB      128         // TOTAL / NDS
#define NSHARED 128
#define KC      64          // K-chunk staged in LDS

// ws layout (floats): [0]=gene acc, [1]=cell acc, [32..35]=zero pad for tail,
// grams start at GRAM_OFF
#define GRAM_OFF 64

typedef __attribute__((ext_vector_type(8)))  short        short8;
typedef __attribute__((ext_vector_type(4)))  unsigned int uint4v;
typedef __attribute__((ext_vector_type(16))) float        f32x16;

typedef const __attribute__((address_space(1))) void* GPTR;
typedef __attribute__((address_space(3))) void*       LPTR;

// DMA global->LDS, 16B per lane, no VGPR transit (spill-proof staging)
#define GLOAD16(gp, lp) \
    __builtin_amdgcn_global_load_lds((GPTR)(gp), (LPTR)(lp), 16, 0, 0)

// ---- fp32 -> bf16 round-half-up, packed pairwise. hh-only MFMA verified
//      rounds 9-18: absmax ~0 vs 3.6e-2 threshold. ----
static __device__ inline unsigned int hpack2(float f0, float f1) {
    const unsigned int u0 = __builtin_bit_cast(unsigned int, f0) + 0x8000u;
    const unsigned int u1 = __builtin_bit_cast(unsigned int, f1) + 0x8000u;
    return (u1 & 0xFFFF0000u) | (u0 >> 16);
}
// read 8 consecutive logical fp32 (two 16B slots, XOR-swizzled) -> bf16x8
static __device__ inline short8 ldcvt_h(const float* base, int sw, int c0) {
    const float4 a = *(const float4*)(base + (((c0    ) ^ sw) << 2));
    const float4 b = *(const float4*)(base + (((c0 + 1) ^ sw) << 2));
    uint4v hv;
    hv[0] = hpack2(a.x, a.y); hv[1] = hpack2(a.z, a.w);
    hv[2] = hpack2(b.x, b.y); hv[3] = hpack2(b.z, b.w);
    return __builtin_bit_cast(short8, hv);
}

// ---------------------------------------------------------------------------
// Fused main kernel (round-13 structure — best measured across 18 rounds).
// Blocks [0, NSHARED): cell-level path (overlaps gram streaming stalls).
// Blocks [NSHARED, NSHARED+NB*splitD): gene-gram path (round-9 K1 core).
// The gram core is pinned ~128us by an invariant per-CU delivery cap:
// falsified levers = transport (DMA vs reg), spill, barrier drain-0 vs
// counted vmcnt, occupancy (2->4 blocks/CU), DRAM granularity (256B->1KB),
// VALU load (32->7%), and L3-resident bf16 staging (round 18). Cross-block
// sync in hot kernels costs 2.2x (round 14: L2 writeback/invalidate).
// grams[(b*splitD + c)][m][64*64], m: 0=xy, 1=xx, 2=yy
// ---------------------------------------------------------------------------
__global__ __launch_bounds__(256, 2)
void k_main(const float* __restrict__ X, const float* __restrict__ Y,
            const float* __restrict__ zsrc, float* __restrict__ grams,
            float* __restrict__ acc, int splitD, int Dper) {
    __shared__ __align__(16) float smem[16384];   // 64 KB exactly
    const int t = threadIdx.x;

    if ((int)blockIdx.x >= NSHARED) {
        // ================= gene-gram path =================
        const int blk = blockIdx.x - NSHARED;
        const int b = blk / splitD, c = blk % splitD;
        const int d0 = c * Dper;
        const int d1 = min(GENES, d0 + Dper);

        const float* __restrict__ xb = X + (size_t)b * NDS * GENES;
        const float* __restrict__ yb = Y + (size_t)b * NDS * GENES;

        float* sX = smem;                  // 2*NDS*KC = 8192 floats (32 KB)
        float* sY = smem + 2 * NDS * KC;   // 32 KB

        const int lane = t & 63;
        const int w    = t >> 6;               // wave 0..3
        const int qr   = w >> 1, qc = w & 1;   // 32x32 output quadrant
        const int lm   = lane & 31;
        const int kh2  = (lane >> 5) << 1;     // k-half offset in 16B slots

        const int mr  = (qr << 5) + lm;        // A-side row
        const int mc  = (qc << 5) + lm;        // B-side row (Gram col)
        const int swr = mr & 15, swc = mc & 15;

        // staging geometry: wave w stages rows [16w,16w+16), 4 instrs/array
        const int s16  = lane & 15;
        const int rsub = lane >> 4;
        const int rA = (w << 4) + rsub;
        const int rB = rA + 4, rC = rA + 8, rD = rA + 12;
        const int cA = (s16 ^ (rA & 15)) << 2;
        const int cB = (s16 ^ (rB & 15)) << 2;
        const int cC = (s16 ^ (rC & 15)) << 2;
        const int cD = (s16 ^ (rD & 15)) << 2;
        const float* gxA = xb + (size_t)rA * GENES + cA;
        const float* gxB = xb + (size_t)rB * GENES + cB;
        const float* gxC = xb + (size_t)rC * GENES + cC;
        const float* gxD = xb + (size_t)rD * GENES + cD;
        const float* gyA = yb + (size_t)rA * GENES + cA;
        const float* gyB = yb + (size_t)rB * GENES + cB;
        const float* gyC = yb + (size_t)rC * GENES + cC;
        const float* gyD = yb + (size_t)rD * GENES + cD;
        const int lA = ((w << 4) + 0) * KC;
        const int lB = lA + 4 * KC, lC = lA + 8 * KC, lD = lA + 12 * KC;

#define STAGEBUF(bofs, dd) do {                                               \
    const float* pxA = ((dd) + cA + 4 <= d1) ? gxA + (dd) : zsrc;             \
    const float* pxB = ((dd) + cB + 4 <= d1) ? gxB + (dd) : zsrc;             \
    const float* pxC = ((dd) + cC + 4 <= d1) ? gxC + (dd) : zsrc;             \
    const float* pxD = ((dd) + cD + 4 <= d1) ? gxD + (dd) : zsrc;             \
    const float* pyA = ((dd) + cA + 4 <= d1) ? gyA + (dd) : zsrc;             \
    const float* pyB = ((dd) + cB + 4 <= d1) ? gyB + (dd) : zsrc;             \
    const float* pyC = ((dd) + cC + 4 <= d1) ? gyC + (dd) : zsrc;             \
    const float* pyD = ((dd) + cD + 4 <= d1) ? gyD + (dd) : zsrc;             \
    GLOAD16(pxA, sX + (bofs) + lA);                                           \
    GLOAD16(pxB, sX + (bofs) + lB);                                           \
    GLOAD16(pxC, sX + (bofs) + lC);                                           \
    GLOAD16(pxD, sX + (bofs) + lD);                                           \
    GLOAD16(pyA, sY + (bofs) + lA);                                           \
    GLOAD16(pyB, sY + (bofs) + lB);                                           \
    GLOAD16(pyC, sY + (bofs) + lC);                                           \
    GLOAD16(pyD, sY + (bofs) + lD);                                           \
} while (0)

        f32x16 axy = {0,0,0,0,0,0,0,0,0,0,0,0,0,0,0,0};
        f32x16 axx = {0,0,0,0,0,0,0,0,0,0,0,0,0,0,0,0};
        f32x16 ayy = {0,0,0,0,0,0,0,0,0,0,0,0,0,0,0,0};

        const int nchunks = (d1 - d0 + KC - 1) / KC;

        STAGEBUF(0, d0);          // prologue: chunk 0 -> buf 0
        __syncthreads();          // vmcnt(0) + barrier: buf 0 ready

        for (int ci = 0; ci < nchunks; ++ci) {
            const int bofs = (ci & 1) * (NDS * KC);
            if (ci + 1 < nchunks)
                STAGEBUF(((ci + 1) & 1) * (NDS * KC), d0 + (ci + 1) * KC);

            const float* xrow = sX + bofs + mr * KC;
            const float* yrow = sY + bofs + mr * KC;
            const float* xcol = sX + bofs + mc * KC;
            const float* ycol = sY + bofs + mc * KC;
#pragma unroll
            for (int ks = 0; ks < 4; ++ks) {
                const int c0 = (ks << 2) + kh2;
                const short8 xr = ldcvt_h(xrow, swr, c0);
                const short8 yr = ldcvt_h(yrow, swr, c0);
                const short8 xc = ldcvt_h(xcol, swc, c0);
                const short8 yc = ldcvt_h(ycol, swc, c0);
                axy = __builtin_amdgcn_mfma_f32_32x32x16_bf16(xr, yc, axy, 0, 0, 0);
                axx = __builtin_amdgcn_mfma_f32_32x32x16_bf16(xr, xc, axx, 0, 0, 0);
                ayy = __builtin_amdgcn_mfma_f32_32x32x16_bf16(yr, yc, ayy, 0, 0, 0);
            }
            __syncthreads();      // drains stage loads + buffer handoff
        }
#undef STAGEBUF

        // writeout: verified 32x32 C/D layout: col=lane&31,
        // row=(reg&3)+8*(reg>>2)+4*(lane>>5)
        float* g = grams + (size_t)(b * splitD + c) * 3 * 4096;
        const int col = (qc << 5) + lm;
#pragma unroll
        for (int r = 0; r < 16; ++r) {
            const int row = (qr << 5) + (r & 3) + ((r >> 2) << 3) + ((lane >> 5) << 2);
            g[0 * 4096 + row * 64 + col] = axy[r];
            g[1 * 4096 + row * 64 + col] = axx[r];
            g[2 * 4096 + row * 64 + col] = ayy[r];
        }
        return;
    }

    // ================= cell-level path (one block per shared gene) =========
    {
        const int s   = blockIdx.x;
        const int col = GENES - NSHARED + s;
        float* lds = smem;                    // 16384 floats

#pragma unroll
        for (int k = 0; k < 32; ++k) {
            const int idx = t + 256 * k;      // = b*64 + n, 0..8191
            lds[idx]        = X[(size_t)idx * GENES + col];
            lds[8192 + idx] = Y[(size_t)idx * GENES + col];
        }
        __syncthreads();

        const int ti = t & 15, tj = t >> 4;
        const int i0 = ti << 2, j0 = tj << 2;
        float axy[4][4] = {{0}}, axx[4][4] = {{0}}, ayy[4][4] = {{0}};

#pragma unroll 4
        for (int bb = 0; bb < NB; ++bb) {
            const float4 xi4 = *(const float4*)(lds + bb * 64 + i0);
            const float4 xj4 = *(const float4*)(lds + bb * 64 + j0);
            const float4 yi4 = *(const float4*)(lds + 8192 + bb * 64 + i0);
            const float4 yj4 = *(const float4*)(lds + 8192 + bb * 64 + j0);
            const float* xi = &xi4.x;
            const float* xj = &xj4.x;
            const float* yi = &yi4.x;
            const float* yj = &yj4.x;
#pragma unroll
            for (int ii = 0; ii < 4; ++ii) {
#pragma unroll
                for (int jj = 0; jj < 4; ++jj) {
                    axy[ii][jj] = fmaf(xi[ii], yj[jj], axy[ii][jj]);
                    axx[ii][jj] = fmaf(xi[ii], xj[jj], axx[ii][jj]);
                    ayy[ii][jj] = fmaf(yi[ii], yj[jj], ayy[ii][jj]);
                }
            }
        }
        __syncthreads();
#pragma unroll
        for (int ii = 0; ii < 4; ++ii) {
            float4 v;
            v.x = axy[ii][0]; v.y = axy[ii][1]; v.z = axy[ii][2]; v.w = axy[ii][3];
            *(float4*)(lds + 0 * 4096 + (i0 + ii) * 64 + j0) = v;
            v.x = axx[ii][0]; v.y = axx[ii][1]; v.z = axx[ii][2]; v.w = axx[ii][3];
            *(float4*)(lds + 1 * 4096 + (i0 + ii) * 64 + j0) = v;
            v.x = ayy[ii][0]; v.y = ayy[ii][1]; v.z = ayy[ii][2]; v.w = ayy[ii][3];
            *(float4*)(lds + 2 * 4096 + (i0 + ii) * 64 + j0) = v;
        }
        __syncthreads();

        float local = 0.f;
#pragma unroll
        for (int k = 0; k < 16; ++k) {
            const int e = t + 256 * k;
            const int i = e >> 6, j = e & 63;
            const float gxy = lds[e];
            const float gxx = lds[4096 + e];
            const float gyy = lds[8192 + e];
            const float nxi = lds[4096 + i * 65], nxj = lds[4096 + j * 65];
            const float nyi = lds[8192 + i * 65], nyj = lds[8192 + j * 65];
            const float dxy = sqrtf(fmaxf(nxi + nyj - 2.f * gxy, 0.f));
            const float dxx = sqrtf(fmaxf(nxi + nxj - 2.f * gxx, 0.f));
            const float dyy = sqrtf(fmaxf(nyi + nyj - 2.f * gyy, 0.f));
            local += dxy - 0.5f * (dxx + dyy);
        }
#pragma unroll
        for (int off = 32; off; off >>= 1) local += __shfl_down(local, off);
        __syncthreads();
        if ((t & 63) == 0) lds[t >> 6] = local;
        __syncthreads();
        if (t == 0) {
            const float bl = lds[0] + lds[1] + lds[2] + lds[3];
            atomicAdd(acc + 1, bl * (1.0f / (4096.0f * (float)NSHARED)));
        }
    }
}

// ---------------------------------------------------------------------------
// K2: per batch — reduce Gram partials, distances, mean, accumulate.
// ---------------------------------------------------------------------------
__global__ __launch_bounds__(256) void k_gene_dist(const float* __restrict__ grams,
                                                   float* __restrict__ acc,
                                                   int splitD) {
    const int b = blockIdx.x, t = threadIdx.x;
    __shared__ __align__(16) float G[3 * 4096];   // 48 KB
    __shared__ float red[4];

    for (int m = 0; m < 3; ++m) {
#pragma unroll
        for (int k = 0; k < 16; ++k) {
            const int e = t + 256 * k;
            float s = 0.f;
            for (int c = 0; c < splitD; ++c)
                s += grams[((size_t)(b * splitD + c) * 3 + m) * 4096 + e];
            G[m * 4096 + e] = s;
        }
    }
    __syncthreads();

    float local = 0.f;
#pragma unroll
    for (int k = 0; k < 16; ++k) {
        const int e = t + 256 * k;
        const int i = e >> 6, j = e & 63;
        const float gxy = G[e];
        const float gxx = G[4096 + e];
        const float gyy = G[8192 + e];
        const float nxi = G[4096 + i * 65], nxj = G[4096 + j * 65];
        const float nyi = G[8192 + i * 65], nyj = G[8192 + j * 65];
        const float dxy = sqrtf(fmaxf(nxi + nyj - 2.f * gxy, 0.f));
        const float dxx = sqrtf(fmaxf(nxi + nxj - 2.f * gxx, 0.f));
        const float dyy = sqrtf(fmaxf(nyi + nyj - 2.f * gyy, 0.f));
        local += dxy - 0.5f * (dxx + dyy);
    }
#pragma unroll
    for (int off = 32; off; off >>= 1) local += __shfl_down(local, off);
    if ((t & 63) == 0) red[t >> 6] = local;
    __syncthreads();
    if (t == 0) {
        const float bl = red[0] + red[1] + red[2] + red[3];
        atomicAdd(acc, bl * (1.0f / (4096.0f * (float)NB)));
    }
}

__global__ void k_final(const float* __restrict__ acc, float* __restrict__ out) {
    out[0] = acc[0] + acc[1];
}

extern "C" void kernel_launch(void* const* d_in, const int* in_sizes, int n_in,
                              void* d_out, int out_size, void* d_ws, size_t ws_size,
                              hipStream_t stream) {
    const float* X = (const float*)d_in[0];
    const float* Y = (const float*)d_in[1];
    float* out = (float*)d_out;
    float* ws  = (float*)d_ws;

    int splitD = 4;
    while (splitD > 1 &&
           ((size_t)GRAM_OFF + (size_t)splitD * NB * 3 * 4096) * sizeof(float) > ws_size)
        splitD >>= 1;
    const int chunks = (GENES + KC - 1) / KC;            // 79
    const int cper   = (chunks + splitD - 1) / splitD;   // chunks per slice
    const int Dper   = cper * KC;                        // multiple of KC

    float* acc   = ws;
    float* zsrc  = ws + 32;          // 16B of zeros (memset covers [0,64))
    float* grams = ws + GRAM_OFF;

    // zero acc + zsrc region (replay-safe; replaces k_zero launch)
    hipMemsetAsync(ws, 0, GRAM_OFF * sizeof(float), stream);
    // fused: cell blocks first (co-resident from t=0, hide under gram stalls)
    hipLaunchKernelGGL(k_main, dim3(NSHARED + NB * splitD), dim3(256), 0, stream,
                       X, Y, zsrc, grams, acc, splitD, Dper);
    hipLaunchKernelGGL(k_gene_dist, dim3(NB), dim3(256), 0, stream,
                       grams, acc + 0, splitD);
    hipLaunchKernelGGL(k_final, dim3(1), dim3(1), 0, stream, acc, out);
}

// Round 20
// 160.154 us; speedup vs baseline: 1.4496x; 1.0031x over previous
//
#include <hip/hip_runtime.h>
#include <math.h>

#define TOTAL   8192
#define GENES   5000
#define NDS     64          // points per cloud
#define NB      128         // TOTAL / NDS
#define NSHARED 128
#define KC      64          // K-chunk staged in LDS

// ws layout (floats): [0]=gene acc, [1]=cell acc, [32..35]=zero pad for tail,
// grams start at GRAM_OFF
#define GRAM_OFF 64

typedef __attribute__((ext_vector_type(8)))  short        short8;
typedef __attribute__((ext_vector_type(4)))  unsigned int uint4v;
typedef __attribute__((ext_vector_type(16))) float        f32x16;

typedef const __attribute__((address_space(1))) void* GPTR;
typedef __attribute__((address_space(3))) void*       LPTR;

// DMA global->LDS, 16B per lane, no VGPR transit (spill-proof staging)
#define GLOAD16(gp, lp) \
    __builtin_amdgcn_global_load_lds((GPTR)(gp), (LPTR)(lp), 16, 0, 0)

// ---- fp32 -> bf16 round-half-up, packed pairwise. hh-only MFMA verified
//      rounds 9-18: absmax ~0 vs 3.6e-2 threshold. ----
static __device__ inline unsigned int hpack2(float f0, float f1) {
    const unsigned int u0 = __builtin_bit_cast(unsigned int, f0) + 0x8000u;
    const unsigned int u1 = __builtin_bit_cast(unsigned int, f1) + 0x8000u;
    return (u1 & 0xFFFF0000u) | (u0 >> 16);
}
// read 8 consecutive logical fp32 (two 16B slots, XOR-swizzled) -> bf16x8
static __device__ inline short8 ldcvt_h(const float* base, int sw, int c0) {
    const float4 a = *(const float4*)(base + (((c0    ) ^ sw) << 2));
    const float4 b = *(const float4*)(base + (((c0 + 1) ^ sw) << 2));
    uint4v hv;
    hv[0] = hpack2(a.x, a.y); hv[1] = hpack2(a.z, a.w);
    hv[2] = hpack2(b.x, b.y); hv[3] = hpack2(b.z, b.w);
    return __builtin_bit_cast(short8, hv);
}

// ---------------------------------------------------------------------------
// Fused main kernel (round-13 structure — best measured across 18 rounds).
// Blocks [0, NSHARED): cell-level path (overlaps gram streaming stalls).
// Blocks [NSHARED, NSHARED+NB*splitD): gene-gram path (round-9 K1 core).
// The gram core is pinned ~128us by an invariant per-CU delivery cap:
// falsified levers = transport (DMA vs reg), spill, barrier drain-0 vs
// counted vmcnt, occupancy (2->4 blocks/CU), DRAM granularity (256B->1KB),
// VALU load (32->7%), and L3-resident bf16 staging (round 18). Cross-block
// sync in hot kernels costs 2.2x (round 14: L2 writeback/invalidate).
// grams[(b*splitD + c)][m][64*64], m: 0=xy, 1=xx, 2=yy
// ---------------------------------------------------------------------------
__global__ __launch_bounds__(256, 2)
void k_main(const float* __restrict__ X, const float* __restrict__ Y,
            const float* __restrict__ zsrc, float* __restrict__ grams,
            float* __restrict__ acc, int splitD, int Dper) {
    __shared__ __align__(16) float smem[16384];   // 64 KB exactly
    const int t = threadIdx.x;

    if ((int)blockIdx.x >= NSHARED) {
        // ================= gene-gram path =================
        const int blk = blockIdx.x - NSHARED;
        const int b = blk / splitD, c = blk % splitD;
        const int d0 = c * Dper;
        const int d1 = min(GENES, d0 + Dper);

        const float* __restrict__ xb = X + (size_t)b * NDS * GENES;
        const float* __restrict__ yb = Y + (size_t)b * NDS * GENES;

        float* sX = smem;                  // 2*NDS*KC = 8192 floats (32 KB)
        float* sY = smem + 2 * NDS * KC;   // 32 KB

        const int lane = t & 63;
        const int w    = t >> 6;               // wave 0..3
        const int qr   = w >> 1, qc = w & 1;   // 32x32 output quadrant
        const int lm   = lane & 31;
        const int kh2  = (lane >> 5) << 1;     // k-half offset in 16B slots

        const int mr  = (qr << 5) + lm;        // A-side row
        const int mc  = (qc << 5) + lm;        // B-side row (Gram col)
        const int swr = mr & 15, swc = mc & 15;

        // staging geometry: wave w stages rows [16w,16w+16), 4 instrs/array
        const int s16  = lane & 15;
        const int rsub = lane >> 4;
        const int rA = (w << 4) + rsub;
        const int rB = rA + 4, rC = rA + 8, rD = rA + 12;
        const int cA = (s16 ^ (rA & 15)) << 2;
        const int cB = (s16 ^ (rB & 15)) << 2;
        const int cC = (s16 ^ (rC & 15)) << 2;
        const int cD = (s16 ^ (rD & 15)) << 2;
        const float* gxA = xb + (size_t)rA * GENES + cA;
        const float* gxB = xb + (size_t)rB * GENES + cB;
        const float* gxC = xb + (size_t)rC * GENES + cC;
        const float* gxD = xb + (size_t)rD * GENES + cD;
        const float* gyA = yb + (size_t)rA * GENES + cA;
        const float* gyB = yb + (size_t)rB * GENES + cB;
        const float* gyC = yb + (size_t)rC * GENES + cC;
        const float* gyD = yb + (size_t)rD * GENES + cD;
        const int lA = ((w << 4) + 0) * KC;
        const int lB = lA + 4 * KC, lC = lA + 8 * KC, lD = lA + 12 * KC;

#define STAGEBUF(bofs, dd) do {                                               \
    const float* pxA = ((dd) + cA + 4 <= d1) ? gxA + (dd) : zsrc;             \
    const float* pxB = ((dd) + cB + 4 <= d1) ? gxB + (dd) : zsrc;             \
    const float* pxC = ((dd) + cC + 4 <= d1) ? gxC + (dd) : zsrc;             \
    const float* pxD = ((dd) + cD + 4 <= d1) ? gxD + (dd) : zsrc;             \
    const float* pyA = ((dd) + cA + 4 <= d1) ? gyA + (dd) : zsrc;             \
    const float* pyB = ((dd) + cB + 4 <= d1) ? gyB + (dd) : zsrc;             \
    const float* pyC = ((dd) + cC + 4 <= d1) ? gyC + (dd) : zsrc;             \
    const float* pyD = ((dd) + cD + 4 <= d1) ? gyD + (dd) : zsrc;             \
    GLOAD16(pxA, sX + (bofs) + lA);                                           \
    GLOAD16(pxB, sX + (bofs) + lB);                                           \
    GLOAD16(pxC, sX + (bofs) + lC);                                           \
    GLOAD16(pxD, sX + (bofs) + lD);                                           \
    GLOAD16(pyA, sY + (bofs) + lA);                                           \
    GLOAD16(pyB, sY + (bofs) + lB);                                           \
    GLOAD16(pyC, sY + (bofs) + lC);                                           \
    GLOAD16(pyD, sY + (bofs) + lD);                                           \
} while (0)

        f32x16 axy = {0,0,0,0,0,0,0,0,0,0,0,0,0,0,0,0};
        f32x16 axx = {0,0,0,0,0,0,0,0,0,0,0,0,0,0,0,0};
        f32x16 ayy = {0,0,0,0,0,0,0,0,0,0,0,0,0,0,0,0};

        const int nchunks = (d1 - d0 + KC - 1) / KC;

        STAGEBUF(0, d0);          // prologue: chunk 0 -> buf 0
        __syncthreads();          // vmcnt(0) + barrier: buf 0 ready

        for (int ci = 0; ci < nchunks; ++ci) {
            const int bofs = (ci & 1) * (NDS * KC);
            if (ci + 1 < nchunks)
                STAGEBUF(((ci + 1) & 1) * (NDS * KC), d0 + (ci + 1) * KC);

            const float* xrow = sX + bofs + mr * KC;
            const float* yrow = sY + bofs + mr * KC;
            const float* xcol = sX + bofs + mc * KC;
            const float* ycol = sY + bofs + mc * KC;
#pragma unroll
            for (int ks = 0; ks < 4; ++ks) {
                const int c0 = (ks << 2) + kh2;
                const short8 xr = ldcvt_h(xrow, swr, c0);
                const short8 yr = ldcvt_h(yrow, swr, c0);
                const short8 xc = ldcvt_h(xcol, swc, c0);
                const short8 yc = ldcvt_h(ycol, swc, c0);
                axy = __builtin_amdgcn_mfma_f32_32x32x16_bf16(xr, yc, axy, 0, 0, 0);
                axx = __builtin_amdgcn_mfma_f32_32x32x16_bf16(xr, xc, axx, 0, 0, 0);
                ayy = __builtin_amdgcn_mfma_f32_32x32x16_bf16(yr, yc, ayy, 0, 0, 0);
            }
            __syncthreads();      // drains stage loads + buffer handoff
        }
#undef STAGEBUF

        // writeout: verified 32x32 C/D layout: col=lane&31,
        // row=(reg&3)+8*(reg>>2)+4*(lane>>5)
        float* g = grams + (size_t)(b * splitD + c) * 3 * 4096;
        const int col = (qc << 5) + lm;
#pragma unroll
        for (int r = 0; r < 16; ++r) {
            const int row = (qr << 5) + (r & 3) + ((r >> 2) << 3) + ((lane >> 5) << 2);
            g[0 * 4096 + row * 64 + col] = axy[r];
            g[1 * 4096 + row * 64 + col] = axx[r];
            g[2 * 4096 + row * 64 + col] = ayy[r];
        }
        return;
    }

    // ================= cell-level path (one block per shared gene) =========
    {
        const int s   = blockIdx.x;
        const int col = GENES - NSHARED + s;
        float* lds = smem;                    // 16384 floats

#pragma unroll
        for (int k = 0; k < 32; ++k) {
            const int idx = t + 256 * k;      // = b*64 + n, 0..8191
            lds[idx]        = X[(size_t)idx * GENES + col];
            lds[8192 + idx] = Y[(size_t)idx * GENES + col];
        }
        __syncthreads();

        const int ti = t & 15, tj = t >> 4;
        const int i0 = ti << 2, j0 = tj << 2;
        float axy[4][4] = {{0}}, axx[4][4] = {{0}}, ayy[4][4] = {{0}};

#pragma unroll 4
        for (int bb = 0; bb < NB; ++bb) {
            const float4 xi4 = *(const float4*)(lds + bb * 64 + i0);
            const float4 xj4 = *(const float4*)(lds + bb * 64 + j0);
            const float4 yi4 = *(const float4*)(lds + 8192 + bb * 64 + i0);
            const float4 yj4 = *(const float4*)(lds + 8192 + bb * 64 + j0);
            const float* xi = &xi4.x;
            const float* xj = &xj4.x;
            const float* yi = &yi4.x;
            const float* yj = &yj4.x;
#pragma unroll
            for (int ii = 0; ii < 4; ++ii) {
#pragma unroll
                for (int jj = 0; jj < 4; ++jj) {
                    axy[ii][jj] = fmaf(xi[ii], yj[jj], axy[ii][jj]);
                    axx[ii][jj] = fmaf(xi[ii], xj[jj], axx[ii][jj]);
                    ayy[ii][jj] = fmaf(yi[ii], yj[jj], ayy[ii][jj]);
                }
            }
        }
        __syncthreads();
#pragma unroll
        for (int ii = 0; ii < 4; ++ii) {
            float4 v;
            v.x = axy[ii][0]; v.y = axy[ii][1]; v.z = axy[ii][2]; v.w = axy[ii][3];
            *(float4*)(lds + 0 * 4096 + (i0 + ii) * 64 + j0) = v;
            v.x = axx[ii][0]; v.y = axx[ii][1]; v.z = axx[ii][2]; v.w = axx[ii][3];
            *(float4*)(lds + 1 * 4096 + (i0 + ii) * 64 + j0) = v;
            v.x = ayy[ii][0]; v.y = ayy[ii][1]; v.z = ayy[ii][2]; v.w = ayy[ii][3];
            *(float4*)(lds + 2 * 4096 + (i0 + ii) * 64 + j0) = v;
        }
        __syncthreads();

        float local = 0.f;
#pragma unroll
        for (int k = 0; k < 16; ++k) {
            const int e = t + 256 * k;
            const int i = e >> 6, j = e & 63;
            const float gxy = lds[e];
            const float gxx = lds[4096 + e];
            const float gyy = lds[8192 + e];
            const float nxi = lds[4096 + i * 65], nxj = lds[4096 + j * 65];
            const float nyi = lds[8192 + i * 65], nyj = lds[8192 + j * 65];
            const float dxy = sqrtf(fmaxf(nxi + nyj - 2.f * gxy, 0.f));
            const float dxx = sqrtf(fmaxf(nxi + nxj - 2.f * gxx, 0.f));
            const float dyy = sqrtf(fmaxf(nyi + nyj - 2.f * gyy, 0.f));
            local += dxy - 0.5f * (dxx + dyy);
        }
#pragma unroll
        for (int off = 32; off; off >>= 1) local += __shfl_down(local, off);
        __syncthreads();
        if ((t & 63) == 0) lds[t >> 6] = local;
        __syncthreads();
        if (t == 0) {
            const float bl = lds[0] + lds[1] + lds[2] + lds[3];
            atomicAdd(acc + 1, bl * (1.0f / (4096.0f * (float)NSHARED)));
        }
    }
}

// ---------------------------------------------------------------------------
// K2: per batch — reduce Gram partials, distances, mean, accumulate.
// ---------------------------------------------------------------------------
__global__ __launch_bounds__(256) void k_gene_dist(const float* __restrict__ grams,
                                                   float* __restrict__ acc,
                                                   int splitD) {
    const int b = blockIdx.x, t = threadIdx.x;
    __shared__ __align__(16) float G[3 * 4096];   // 48 KB
    __shared__ float red[4];

    for (int m = 0; m < 3; ++m) {
#pragma unroll
        for (int k = 0; k < 16; ++k) {
            const int e = t + 256 * k;
            float s = 0.f;
            for (int c = 0; c < splitD; ++c)
                s += grams[((size_t)(b * splitD + c) * 3 + m) * 4096 + e];
            G[m * 4096 + e] = s;
        }
    }
    __syncthreads();

    float local = 0.f;
#pragma unroll
    for (int k = 0; k < 16; ++k) {
        const int e = t + 256 * k;
        const int i = e >> 6, j = e & 63;
        const float gxy = G[e];
        const float gxx = G[4096 + e];
        const float gyy = G[8192 + e];
        const float nxi = G[4096 + i * 65], nxj = G[4096 + j * 65];
        const float nyi = G[8192 + i * 65], nyj = G[8192 + j * 65];
        const float dxy = sqrtf(fmaxf(nxi + nyj - 2.f * gxy, 0.f));
        const float dxx = sqrtf(fmaxf(nxi + nxj - 2.f * gxx, 0.f));
        const float dyy = sqrtf(fmaxf(nyi + nyj - 2.f * gyy, 0.f));
        local += dxy - 0.5f * (dxx + dyy);
    }
#pragma unroll
    for (int off = 32; off; off >>= 1) local += __shfl_down(local, off);
    if ((t & 63) == 0) red[t >> 6] = local;
    __syncthreads();
    if (t == 0) {
        const float bl = red[0] + red[1] + red[2] + red[3];
        atomicAdd(acc, bl * (1.0f / (4096.0f * (float)NB)));
    }
}

__global__ void k_final(const float* __restrict__ acc, float* __restrict__ out) {
    out[0] = acc[0] + acc[1];
}

extern "C" void kernel_launch(void* const* d_in, const int* in_sizes, int n_in,
                              void* d_out, int out_size, void* d_ws, size_t ws_size,
                              hipStream_t stream) {
    const float* X = (const float*)d_in[0];
    const float* Y = (const float*)d_in[1];
    float* out = (float*)d_out;
    float* ws  = (float*)d_ws;

    int splitD = 4;
    while (splitD > 1 &&
           ((size_t)GRAM_OFF + (size_t)splitD * NB * 3 * 4096) * sizeof(float) > ws_size)
        splitD >>= 1;
    const int chunks = (GENES + KC - 1) / KC;            // 79
    const int cper   = (chunks + splitD - 1) / splitD;   // chunks per slice
    const int Dper   = cper * KC;                        // multiple of KC

    float* acc   = ws;
    float* zsrc  = ws + 32;          // 16B of zeros (memset covers [0,64))
    float* grams = ws + GRAM_OFF;

    // zero acc + zsrc region (replay-safe; replaces k_zero launch)
    hipMemsetAsync(ws, 0, GRAM_OFF * sizeof(float), stream);
    // fused: cell blocks first (co-resident from t=0, hide under gram stalls)
    hipLaunchKernelGGL(k_main, dim3(NSHARED + NB * splitD), dim3(256), 0, stream,
                       X, Y, zsrc, grams, acc, splitD, Dper);
    hipLaunchKernelGGL(k_gene_dist, dim3(NB), dim3(256), 0, stream,
                       grams, acc + 0, splitD);
    hipLaunchKernelGGL(k_final, dim3(1), dim3(1), 0, stream, acc, out);
}